// Round 5
// baseline (293.498 us; speedup 1.0000x reference)
//
#include <hip/hip_runtime.h>
#include <math.h>

// Problem constants (fixed by setup_inputs)
constexpr int B    = 2;
constexpr int W    = 16;
constexpr int N    = 1000;
constexpr int FIN  = 16;
constexpr int E    = 16000;
constexpr int DE   = 8;
constexpr int H    = 128;   // hidden
constexpr int L    = 3;
// Window pruning: temporal edges go t -> t+1 and head reads only w=15;
// 3 layers => only global windows 12..15 matter.
constexpr int WL   = 4;          // local windows kept (global 12..15)
constexpr int W0G  = 12;         // first kept global window
constexpr int RPB  = WL * N;     // rows per batch = 4000
constexpr int ROWS = B * RPB;    // 8000
constexpr int NMAT = 12;         // transposed mats: (q,k,v,o) x 3 layers

// ---------------- helpers ----------------
__device__ __forceinline__ float blockSum128(float v) {
  #pragma unroll
  for (int off = 32; off >= 1; off >>= 1) v += __shfl_xor(v, off);
  __shared__ float s2[2];
  int w = threadIdx.x >> 6;
  __syncthreads();  // protect s2 reuse across multiple calls
  if ((threadIdx.x & 63) == 0) s2[w] = v;
  __syncthreads();
  return s2[0] + s2[1];
}

// DPP quad-perm butterfly adds (VALU pipe, not DS)
__device__ __forceinline__ float dpp_add_xor1(float x) {
  int y = __builtin_amdgcn_update_dpp(0, __float_as_int(x), 0xB1, 0xF, 0xF, true);
  return x + __int_as_float(y);  // quad_perm [1,0,3,2]
}
__device__ __forceinline__ float dpp_add_xor2(float x) {
  int y = __builtin_amdgcn_update_dpp(0, __float_as_int(x), 0x4E, 0xF, 0xF, true);
  return x + __int_as_float(y);  // quad_perm [2,3,0,1]
}
__device__ __forceinline__ float headSum32(float p) {
  p = dpp_add_xor1(p);
  p = dpp_add_xor2(p);
  p += __shfl_xor(p, 4);
  p += __shfl_xor(p, 8);
  p += __shfl_xor(p, 16);
  return p;
}
__device__ __forceinline__ float dot4(float4 a, float4 b) {
  return a.x * b.x + a.y * b.y + a.z * b.z + a.w * b.w;
}

// ------- graph count+scan (1 block; reads only dst row, prefetched) -------
__global__ void k_count_scan(const int* __restrict__ ei, int* __restrict__ offs,
                             int* __restrict__ cursor, float* __restrict__ meanea) {
  __shared__ int cnt[N];
  __shared__ int scn[1024];
  int t = threadIdx.x;  // 0..1023
  if (t < 8) meanea[t] = 0.f;     // zero accumulator for k_prep2's atomics
  if (t < N) cnt[t] = 0;
  __syncthreads();
  int vals[16];
  int nv = 0;
  for (int e = t; e < E; e += 1024) vals[nv++] = ei[E + e];
  for (int i = 0; i < nv; i++) atomicAdd(&cnt[vals[i]], 1);
  __syncthreads();
  int v = (t < N) ? cnt[t] : 0;
  scn[t] = v;
  __syncthreads();
  for (int st = 1; st < 1024; st <<= 1) {
    int add = (t >= st) ? scn[t - st] : 0;
    __syncthreads();
    scn[t] += add;
    __syncthreads();
  }
  if (t < N) {
    offs[t + 1] = scn[t];
    if (t == 0) offs[0] = 0;
    cursor[t] = scn[t] - v;
  }
}

// ------- prep2: CSR fill | easum | weight transposes (k-packed) | input proj -------
// wTp layout per mat: float4 wTp4[(mat*32 + kk4)*H + c] = {w[4kk4][c],w[4kk4+1][c],w[4kk4+2][c],w[4kk4+3][c]}
__global__ void k_prep2(const int* __restrict__ ei, const float* __restrict__ ea,
                        int* __restrict__ cursor, int* __restrict__ csr_src,
                        int* __restrict__ csr_eid, float* __restrict__ meanea,
                        const float* __restrict__ qw, const float* __restrict__ kw,
                        const float* __restrict__ vw, const float* __restrict__ ow,
                        float4* __restrict__ wTp4,
                        const float* __restrict__ xw, const float* __restrict__ in_w,
                        const float* __restrict__ in_b, float* __restrict__ x) {
  int bid = blockIdx.x;
  int t = threadIdx.x;  // 256 threads
  if (bid < 64) {
    // CSR fill
    int e = bid * 256 + t;
    if (e < E) {
      int src = ei[e];
      int dst = ei[E + e];
      int pos = atomicAdd(&cursor[dst], 1);
      csr_src[pos] = src;
      csr_eid[pos] = e;
    }
  } else if (bid < 128) {
    // ea column sums
    __shared__ float sbuf[256];
    int d = t & 7, g = t >> 3;
    float s = 0.f;
    for (int e = (bid - 64) * 32 + g; e < E; e += 64 * 32) s += ea[e * DE + d];
    sbuf[t] = s;
    __syncthreads();
    for (int st = 16; st >= 1; st >>= 1) {
      if (g < st) sbuf[g * 8 + d] += sbuf[(g + st) * 8 + d];
      __syncthreads();
    }
    if (g == 0) atomicAdd(&meanea[d], sbuf[d]);
  } else if (bid < 128 + NMAT * 16) {
    // weight transpose into k-packed layout
    int bid2 = bid - 128;
    int mat = bid2 / 16;
    int pair = bid2 % 16;
    int kk4 = pair * 2 + (t >> 7);  // 0..31
    int c = t & 127;
    int l = mat >> 2, mm = mat & 3;
    const float* src = ((mm == 0) ? qw : (mm == 1) ? kw : (mm == 2) ? vw : ow) + (long)l * H * H;
    int k0 = kk4 * 4;
    float4 v4;
    v4.x = src[(k0 + 0) * H + c];
    v4.y = src[(k0 + 1) * H + c];
    v4.z = src[(k0 + 2) * H + c];
    v4.w = src[(k0 + 3) * H + c];
    wTp4[((long)mat * 32 + kk4) * H + c] = v4;
  } else {
    // input projection: x = xw @ in_w + in_b  (64-row tiles)
    int bi = bid - (128 + NMAT * 16);  // 0..125
    int b = bi / 63, tt = bi % 63;
    int lr0 = tt * 64;
    __shared__ float xwS[64][FIN];
    __shared__ float inS[FIN][H];
    for (int i = t; i < 64 * FIN; i += 256) {
      int r = i >> 4, k = i & 15;
      int lr = lr0 + r;
      float val = 0.f;
      if (lr < RPB) {
        int wl = lr / N, n = lr % N;
        val = xw[(((long)b * W + (W0G + wl)) * N + n) * FIN + k];
      }
      xwS[r][k] = val;
    }
    for (int i = t; i < FIN * H; i += 256) inS[i >> 7][i & 127] = in_w[i];
    __syncthreads();
    #pragma unroll
    for (int qi = 0; qi < 8; qi++) {
      int idx = t + qi * 256;        // 0..2047
      int r = idx >> 5, cq = idx & 31;
      int lr = lr0 + r;
      if (lr < RPB) {
        float4 acc = *(const float4*)(in_b + cq * 4);
        #pragma unroll
        for (int k = 0; k < FIN; k++) {
          float xv = xwS[r][k];
          float4 w4 = *(const float4*)(&inS[k][cq * 4]);
          acc.x += xv * w4.x; acc.y += xv * w4.y; acc.z += xv * w4.z; acc.w += xv * w4.w;
        }
        *(float4*)(x + ((long)b * RPB + lr) * H + cq * 4) = acc;
      }
    }
  }
}

// ---------------- tiled GEMM: C = X @ W + b ----------------
// 64 rows x 128 cols per block, 256 threads, 8-row x 4-col register tile.
__global__ void k_gemm(const float* __restrict__ X, const float4* __restrict__ wTp4,
                       int matBase,  // (l*4) : q,k,v are matBase+0,1,2
                       const float* __restrict__ bq, const float* __restrict__ bk,
                       const float* __restrict__ bv,
                       float* __restrict__ Cq, float* __restrict__ Ck, float* __restrict__ Cv,
                       int base, int tiles) {
  int m = blockIdx.y;
  const float* bm = (m == 0) ? bq : (m == 1) ? bk : bv;
  float* Cm       = (m == 0) ? Cq : (m == 1) ? Ck : Cv;
  const float4* wp = wTp4 + (long)(matBase + m) * 32 * H;
  int bb = blockIdx.x / tiles;
  int tt = blockIdx.x % tiles;
  int lr0 = base + tt * 64;
  int t = threadIdx.x;
  int cg = t & 31, rg = t >> 5;  // col-group (4 cols), row-group (8 rows)
  __shared__ float xs[64][H];
  // stage 64 rows of X
  #pragma unroll
  for (int i = 0; i < 8; i++) {
    int row = i * 8 + rg;
    int lr = lr0 + row;
    float4 v4 = make_float4(0.f, 0.f, 0.f, 0.f);
    if (lr < RPB) v4 = *(const float4*)(X + ((long)bb * RPB + lr) * H + cg * 4);
    *(float4*)&xs[row][cg * 4] = v4;
  }
  __syncthreads();
  float4 bias4 = *(const float4*)(bm + cg * 4);
  float4 acc[8];
  #pragma unroll
  for (int i = 0; i < 8; i++) acc[i] = bias4;
  for (int kk4 = 0; kk4 < 32; kk4++) {
    float4 w0 = wp[kk4 * H + cg * 4 + 0];
    float4 w1 = wp[kk4 * H + cg * 4 + 1];
    float4 w2 = wp[kk4 * H + cg * 4 + 2];
    float4 w3 = wp[kk4 * H + cg * 4 + 3];
    #pragma unroll
    for (int i = 0; i < 8; i++) {
      float4 xv = *(const float4*)&xs[rg * 8 + i][kk4 * 4];
      acc[i].x += dot4(xv, w0);
      acc[i].y += dot4(xv, w1);
      acc[i].z += dot4(xv, w2);
      acc[i].w += dot4(xv, w3);
    }
  }
  #pragma unroll
  for (int i = 0; i < 8; i++) {
    int lr = lr0 + rg * 8 + i;
    if (lr < RPB) *(float4*)(Cm + ((long)bb * RPB + lr) * H + cg * 4) = acc[i];
  }
}

// ------- fused: attention (gather, online softmax, register-FiLM, 4-edge ILP)
//         + O-proj (k-packed owT) + residual + LN (+ optional softplus head) -------
__global__ void k_attn_oln(const float* __restrict__ Qb, const float* __restrict__ Kb,
                           const float* __restrict__ Vb,
                           const float* __restrict__ ea, const float* __restrict__ meanea,
                           const float* __restrict__ fw, const float* __restrict__ fb,
                           const int* __restrict__ offs, const int* __restrict__ csr_src,
                           const int* __restrict__ csr_eid,
                           const float* __restrict__ x, const float4* __restrict__ owp,
                           const float* __restrict__ ob, const float* __restrict__ lng,
                           const float* __restrict__ lnb, float* __restrict__ xo,
                           int out_lo,
                           const float* __restrict__ hw, const float* __restrict__ hb,
                           float* __restrict__ out, int do_head) {
  int tid = threadIdx.x;  // tid = h*32 + d
  // FiLM weights for this lane's channel -> registers (16 VGPRs)
  float rgw[DE], rbw[DE];
  #pragma unroll
  for (int d = 0; d < DE; d++) {
    rgw[d] = fw[d * 2 * H + tid];
    rbw[d] = fw[d * 2 * H + H + tid];
  }
  int nwin = WL - out_lo;
  int idx = blockIdx.x;
  int b = idx / (nwin * N);
  int rem = idx % (nwin * N);
  int wl = out_lo + rem / N;
  int n = rem % N;
  long drow = ((long)b * WL + wl) * N + n;
  float q = Qb[drow * H + tid];
  float fbg = fb[tid], fbb = fb[H + tid];
  long sbase = ((long)b * WL + wl) * N;          // spatial src rows (same window)
  long trow  = ((long)b * WL + wl - 1) * N + n;  // temporal src row
  const float scale = 0.17677669529663687f;      // 1/sqrt(32)
  int i0 = offs[n], i1 = offs[n + 1];            // edge i1 == temporal edge

  float m = -INFINITY, ssum = 0.f, acc = 0.f;
  for (int base = i0; base <= i1; base += 4) {
    float l[4], vv[4];
    #pragma unroll
    for (int j = 0; j < 4; j++) {
      int i = base + j;
      if (i > i1) { l[j] = -INFINITY; vv[j] = 0.f; continue; }  // block-uniform
      long srow; const float* eap; float esc;
      if (i < i1) { srow = sbase + csr_src[i]; eap = ea + (long)csr_eid[i] * DE; esc = 1.f; }
      else        { srow = trow;               eap = meanea;                    esc = 1.f / E; }
      float kv = Kb[srow * H + tid];
      vv[j]    = Vb[srow * H + tid];
      float4 a0 = *(const float4*)(eap);
      float4 a1 = *(const float4*)(eap + 4);
      float a[DE] = {a0.x * esc, a0.y * esc, a0.z * esc, a0.w * esc,
                     a1.x * esc, a1.y * esc, a1.z * esc, a1.w * esc};
      float g = fbg, be = fbb;
      #pragma unroll
      for (int d = 0; d < DE; d++) {
        g  += a[d] * rgw[d];
        be += a[d] * rbw[d];
      }
      float p = q * (kv * (1.f + g) + be);
      l[j] = headSum32(p) * scale;
    }
    float mn = m;
    #pragma unroll
    for (int j = 0; j < 4; j++) mn = fmaxf(mn, l[j]);
    float sc  = __expf(m - mn);
    float pe0 = __expf(l[0] - mn);
    float pe1 = __expf(l[1] - mn);
    float pe2 = __expf(l[2] - mn);
    float pe3 = __expf(l[3] - mn);
    ssum = ssum * sc + ((pe0 + pe1) + (pe2 + pe3));
    acc  = acc  * sc + ((pe0 * vv[0] + pe1 * vv[1]) + (pe2 * vv[2] + pe3 * vv[3]));
    m = mn;
  }
  float ab = acc / (ssum + 1e-16f);

  // ---- O-projection via k-packed owT: y[c] = ob[c] + sum_k ab[k] ow[k][c] ----
  __shared__ float sab[H];
  sab[tid] = ab;
  __syncthreads();
  float y = ob[tid];
  #pragma unroll 4
  for (int kk4 = 0; kk4 < 32; kk4++) {
    float4 w4 = owp[kk4 * H + tid];
    float4 a4 = *(const float4*)&sab[kk4 * 4];
    y += dot4(a4, w4);
  }

  // ---- residual + layernorm ----
  float v = x[drow * H + tid] + y;
  float mu = blockSum128(v) * (1.f / H);
  float dv = v - mu;
  float var = blockSum128(dv * dv) * (1.f / H);
  float o = dv * rsqrtf(var + 1e-5f) * lng[tid] + lnb[tid];

  if (!do_head) {
    xo[drow * H + tid] = o;
  } else {
    float hv = o * hw[tid];
    float tot = blockSum128(hv);
    if (tid == 0) {
      float z = tot + hb[0];
      out[b * N + n] = fmaxf(z, 0.f) + log1pf(expf(-fabsf(z)));  // softplus
    }
  }
}

// ---------------- launch ----------------
extern "C" void kernel_launch(void* const* d_in, const int* in_sizes, int n_in,
                              void* d_out, int out_size, void* d_ws, size_t ws_size,
                              hipStream_t stream) {
  const float* xw   = (const float*)d_in[0];
  const int*   ei   = (const int*)d_in[1];
  const float* ea   = (const float*)d_in[2];
  const float* in_w = (const float*)d_in[3];
  const float* in_b = (const float*)d_in[4];
  const float* qw   = (const float*)d_in[5];
  const float* qb   = (const float*)d_in[6];
  const float* kw   = (const float*)d_in[7];
  const float* kb   = (const float*)d_in[8];
  const float* vw   = (const float*)d_in[9];
  const float* vb   = (const float*)d_in[10];
  const float* fw   = (const float*)d_in[11];
  const float* fb   = (const float*)d_in[12];
  const float* ow   = (const float*)d_in[13];
  const float* ob   = (const float*)d_in[14];
  const float* ln_g = (const float*)d_in[15];
  const float* ln_b = (const float*)d_in[16];
  const float* hw   = (const float*)d_in[17];
  const float* hb   = (const float*)d_in[18];
  float* out = (float*)d_out;

  // workspace carve-up (float4-aligned chunks first)
  float* ws   = (float*)d_ws;
  float* x    = ws;
  float* x2   = x  + (long)ROWS * H;
  float* Qb   = x2 + (long)ROWS * H;
  float* Kb   = Qb + (long)ROWS * H;
  float* Vb   = Kb + (long)ROWS * H;
  float* wTp  = Vb + (long)ROWS * H;            // 12 mats x 128 x 128
  float* meanea = wTp + (long)NMAT * H * H;     // 8 floats
  int* offs    = (int*)(meanea + 8);
  int* cursor  = offs + N + 1;
  int* csr_src = cursor + N;
  int* csr_eid = csr_src + E;
  float4* wTp4 = (float4*)wTp;

  k_count_scan<<<1, 1024, 0, stream>>>(ei, offs, cursor, meanea);
  k_prep2<<<128 + NMAT * 16 + 126, 256, 0, stream>>>(
      ei, ea, cursor, csr_src, csr_eid, meanea,
      qw, kw, vw, ow, wTp4, xw, in_w, in_b, x);

  float* xa = x;
  float* xb = x2;
  for (int l = 0; l < L; l++) {
    int in_lo = l, out_lo = l + 1;
    int rows_pb = (WL - in_lo) * N;
    int tiles = (rows_pb + 63) / 64;
    k_gemm<<<dim3(B * tiles, 3), 256, 0, stream>>>(
        xa, wTp4, l * 4, qb + (long)l * H, kb + (long)l * H, vb + (long)l * H,
        Qb, Kb, Vb, in_lo * N, tiles);
    int nout = B * (WL - out_lo) * N;
    int last = (l == L - 1) ? 1 : 0;
    k_attn_oln<<<nout, H, 0, stream>>>(
        Qb, Kb, Vb, ea, meanea,
        fw + (long)l * DE * 2 * H, fb + (long)l * 2 * H,
        offs, csr_src, csr_eid,
        xa, wTp4 + ((long)l * 4 + 3) * 32 * H, ob + (long)l * H,
        ln_g + (long)l * H, ln_b + (long)l * H, xb, out_lo,
        hw, hb, out, last);
    float* tmp = xa; xa = xb; xb = tmp;
  }
}